// Round 1
// baseline (1951.486 us; speedup 1.0000x reference)
//
#include <hip/hip_runtime.h>

// Problem constants
#define CC    128          // channels
#define LDIM  361          // l   (stage-A contraction)
#define MDIM  361          // m   (spectral bins, = NLON/2+1)
#define KDIM  361          // k   (nlat output of einsum)
#define NLON  720
#define MR    (2*MDIM)     // 722  interleaved (m, re/im)
#define CK    (CC*KDIM)    // 46208 rows of stage-B GEMM (also = CC*LDIM)

// ---------------------------------------------------------------------------
// Kernel 1: DFT synthesis table  T[mr][j], mr = 2m+r
//   m=0      : re weight 1, im ignored
//   m=360    : re weight cos(pi j) = (-1)^j (Nyquist), im ignored
//   else     : 2*cos(2pi m j/720), -2*sin(2pi m j/720)
// Integer phase reduction keeps the sinf/cosf argument in [0, 2pi): exact.
__global__ void sht_table_kernel(float* __restrict__ T) {
    int idx = blockIdx.x * 256 + threadIdx.x;
    if (idx >= MR * NLON) return;
    int mr = idx / NLON;
    int j  = idx - mr * NLON;
    int m  = mr >> 1;
    int im = mr & 1;
    float v;
    if (m == 0) {
        v = im ? 0.0f : 1.0f;
    } else if (m == MDIM - 1) {
        v = im ? 0.0f : ((j & 1) ? -1.0f : 1.0f);
    } else {
        int ph = (m * j) % NLON;
        float ang = (float)ph * (float)(6.283185307179586 / (double)NLON);
        v = im ? (-2.0f * sinf(ang)) : (2.0f * cosf(ang));
    }
    T[idx] = v;
}

// ---------------------------------------------------------------------------
// Kernel 2: stage A — per-m GEMM
//   xsT[(2m+r)*CK + c*KDIM + k] = sum_l x[((c*LDIM+l)*MDIM+m)*2 + r] * pct[(m*LDIM+l)*KDIM+k]
// Block: one m, 64 rows (32 c x 2 r), 64 k. 256 threads, 4x4 micro-tile.
__global__ __launch_bounds__(256)
void sht_stageA_kernel(const float* __restrict__ x, const float* __restrict__ pct,
                       float* __restrict__ xsT) {
    __shared__ float As[16][66];   // [ll][row], row = cc*2 + r  (+2 pad)
    __shared__ float Bs[16][64];   // [ll][kk]

    const int m  = blockIdx.z;
    const int k0 = blockIdx.x * 64;
    const int c0 = blockIdx.y * 32;
    const int t  = threadIdx.x;
    const int tr = t >> 4;   // 0..15 (row group)
    const int tc = t & 15;   // 0..15 (col group)

    float acc[4][4] = {{0.f}};

    for (int l0 = 0; l0 < LDIM; l0 += 16) {
        // A tile: 32 cc x 16 ll, float2 over r -> 512 pairs, 2/thread
        #pragma unroll
        for (int jj = 0; jj < 2; ++jj) {
            int p  = t + 256 * jj;      // 0..511
            int ll = p & 15;
            int cc = p >> 4;            // 0..31
            int l  = l0 + ll;
            float2 v = make_float2(0.f, 0.f);
            if (l < LDIM) {
                const float* src = x + ((size_t)((c0 + cc) * LDIM + l) * MDIM + m) * 2;
                v = *(const float2*)src;
            }
            As[ll][cc * 2 + 0] = v.x;
            As[ll][cc * 2 + 1] = v.y;
        }
        // B tile: 16 ll x 64 kk, 4/thread, coalesced over k
        #pragma unroll
        for (int jj = 0; jj < 4; ++jj) {
            int p  = t + 256 * jj;
            int kk = p & 63;
            int ll = p >> 6;
            int l  = l0 + ll;
            int k  = k0 + kk;
            float v = 0.f;
            if (l < LDIM && k < KDIM)
                v = pct[((size_t)m * LDIM + l) * KDIM + k];
            Bs[ll][kk] = v;
        }
        __syncthreads();

        #pragma unroll 4
        for (int ll = 0; ll < 16; ++ll) {
            float a[4], b[4];
            #pragma unroll
            for (int i = 0; i < 4; ++i) a[i] = As[ll][tr + 16 * i];
            #pragma unroll
            for (int i = 0; i < 4; ++i) b[i] = Bs[ll][tc + 16 * i];
            #pragma unroll
            for (int i = 0; i < 4; ++i)
                #pragma unroll
                for (int j = 0; j < 4; ++j)
                    acc[i][j] += a[i] * b[j];
        }
        __syncthreads();
    }

    // store: row = tr+16i -> c = c0 + row/2, r = row&1 ; col = k0 + tc + 16j
    #pragma unroll
    for (int i = 0; i < 4; ++i) {
        int row = tr + 16 * i;
        int c   = c0 + (row >> 1);
        int r   = row & 1;
        size_t base = (size_t)(2 * m + r) * CK + (size_t)c * KDIM;
        #pragma unroll
        for (int j = 0; j < 4; ++j) {
            int k = k0 + tc + 16 * j;
            if (k < KDIM) xsT[base + k] = acc[i][j];
        }
    }
}

// ---------------------------------------------------------------------------
// Kernel 3: stage B — DFT-as-GEMM
//   out[row*NLON + j] = sum_mr xsT[mr*CK + row] * T[mr*NLON + j]
// M=46208 (722 tiles of 64, exact), N=720 (12 tiles, guarded), K=722.
__global__ __launch_bounds__(256)
void sht_stageB_kernel(const float* __restrict__ xsT, const float* __restrict__ T,
                       float* __restrict__ out) {
    __shared__ float As[16][64];   // [ll][row-in-tile]
    __shared__ float Bs[16][64];   // [ll][j-in-tile]

    const int j0   = blockIdx.x * 64;
    const int row0 = blockIdx.y * 64;
    const int t    = threadIdx.x;
    const int tr   = t >> 4;
    const int tc   = t & 15;

    float acc[4][4] = {{0.f}};

    for (int l0 = 0; l0 < MR; l0 += 16) {
        #pragma unroll
        for (int jj = 0; jj < 4; ++jj) {
            int p  = t + 256 * jj;
            int i  = p & 63;
            int ll = p >> 6;
            int mr = l0 + ll;
            As[ll][i] = (mr < MR) ? xsT[(size_t)mr * CK + row0 + i] : 0.f;
            int jc = j0 + i;
            Bs[ll][i] = (mr < MR && jc < NLON) ? T[(size_t)mr * NLON + jc] : 0.f;
        }
        __syncthreads();

        #pragma unroll 4
        for (int ll = 0; ll < 16; ++ll) {
            float a[4], b[4];
            #pragma unroll
            for (int i = 0; i < 4; ++i) a[i] = As[ll][tr + 16 * i];
            #pragma unroll
            for (int i = 0; i < 4; ++i) b[i] = Bs[ll][tc + 16 * i];
            #pragma unroll
            for (int i = 0; i < 4; ++i)
                #pragma unroll
                for (int j = 0; j < 4; ++j)
                    acc[i][j] += a[i] * b[j];
        }
        __syncthreads();
    }

    #pragma unroll
    for (int i = 0; i < 4; ++i) {
        int row = row0 + tr + 16 * i;           // always < CK (722 exact tiles)
        #pragma unroll
        for (int j = 0; j < 4; ++j) {
            int jc = j0 + tc + 16 * j;
            if (jc < NLON) out[(size_t)row * NLON + jc] = acc[i][j];
        }
    }
}

// ---------------------------------------------------------------------------
extern "C" void kernel_launch(void* const* d_in, const int* in_sizes, int n_in,
                              void* d_out, int out_size, void* d_ws, size_t ws_size,
                              hipStream_t stream) {
    const float* x   = (const float*)d_in[0];   // [1,128,361,361,2] fp32
    const float* pct = (const float*)d_in[1];   // [361,361,361] fp32
    float* out = (float*)d_out;                 // [1,128,361,720] fp32

    float* xsT = (float*)d_ws;                          // MR*CK floats (133.4 MB)
    float* T   = xsT + (size_t)MR * CK;                 // MR*NLON floats (2.1 MB)

    // Table (independent of stage A)
    sht_table_kernel<<<(MR * NLON + 255) / 256, 256, 0, stream>>>(T);

    // Stage A: 361 per-m GEMMs
    dim3 gA(6 /*k tiles*/, 4 /*row tiles*/, MDIM);
    sht_stageA_kernel<<<gA, 256, 0, stream>>>(x, pct, xsT);

    // Stage B: DFT GEMM
    dim3 gB(12 /*j tiles*/, CK / 64 /*=722 row tiles*/);
    sht_stageB_kernel<<<gB, 256, 0, stream>>>(xsT, T, out);
}

// Round 2
// 725.888 us; speedup vs baseline: 2.6884x; 2.6884x over previous
//
#include <hip/hip_runtime.h>
#include <cstddef>

#define CC   128
#define LDIM 361
#define MDIM 361
#define KDIM 361
#define NLON 720
#define LP   384          // padded l (stage A K-dim)
#define MRP  736          // padded mr (stage B K-dim)
#define NP   768          // padded n (stage B N-dim)
#define CK   (CC*KDIM)    // 46208
#define CR   (2*CC)       // 256

typedef __attribute__((ext_vector_type(8))) short short8;
typedef __attribute__((ext_vector_type(4))) float floatx4;

__device__ __forceinline__ unsigned short f2bf(float f) {
    union { float f; unsigned u; } v; v.f = f;
    unsigned u = v.u;
    u += 0x7fffu + ((u >> 16) & 1u);   // RNE
    return (unsigned short)(u >> 16);
}

__device__ __forceinline__ void async_copy16(const void* g, void* l) {
    __builtin_amdgcn_global_load_lds(
        (const __attribute__((address_space(1))) void*)g,
        (__attribute__((address_space(3))) void*)l, 16, 0, 0);
}

// ---------------------------------------------------------------------------
// Tp[n][mr] bf16, n<720 & mr<722 real weights, else 0 (pad kills xs poison).
__global__ void sht_gen_T(unsigned short* __restrict__ Tp) {
    int idx = blockIdx.x * 256 + threadIdx.x;
    if (idx >= NP * MRP) return;
    int n = idx / MRP, mr = idx - n * MRP;
    float v = 0.f;
    if (n < NLON && mr < 2 * MDIM) {
        int m = mr >> 1, im = mr & 1;
        if (m == 0)            v = im ? 0.f : 1.f;
        else if (m == MDIM-1)  v = im ? 0.f : ((n & 1) ? -1.f : 1.f);
        else {
            int ph = (m * n) % NLON;
            float ang = (float)ph * (float)(3.14159265358979323846 / 360.0);
            v = im ? (-2.f * sinf(ang)) : (2.f * cosf(ang));
        }
    }
    Tp[idx] = f2bf(v);
}

// ---------------------------------------------------------------------------
// x fp32 [c][l][m][r] -> xA bf16 [m][cr=2c+r][LP]  (l-fast, zero pad l>=361)
__global__ __launch_bounds__(256)
void sht_prep_x(const float* __restrict__ x, unsigned short* __restrict__ xA) {
    __shared__ float2 tile[64][33];    // [l][m]
    const int mt = blockIdx.x;         // 0..11
    const int lt = blockIdx.y;         // 0..5
    const int c  = blockIdx.z;         // 0..127
    const int t  = threadIdx.x;

    #pragma unroll
    for (int u = 0; u < 8; ++u) {
        int p  = t + 256 * u;
        int li = p >> 5, mi = p & 31;
        int l = lt * 64 + li, m = mt * 32 + mi;
        float2 v = make_float2(0.f, 0.f);
        if (l < LDIM && m < MDIM)
            v = *(const float2*)(x + ((size_t)(c * LDIM + l) * MDIM + m) * 2);
        tile[li][mi] = v;
    }
    __syncthreads();

    #pragma unroll
    for (int u = 0; u < 2; ++u) {
        int s  = t + 256 * u;          // 0..511
        int mi = s >> 4, rr = (s >> 3) & 1, lo = (s & 7) * 8;
        int m = mt * 32 + mi;
        if (m >= MDIM) continue;
        short8 h;
        #pragma unroll
        for (int e = 0; e < 8; ++e) {
            float2 p = tile[lo + e][mi];
            h[e] = (short)f2bf(rr ? p.y : p.x);
        }
        *(short8*)(xA + ((size_t)m * CR + 2 * c + rr) * LP + lt * 64 + lo) = h;
    }
}

// ---------------------------------------------------------------------------
// Stage A: per-m GEMM  D[cr][k] = sum_l xA[m][cr][l] * pct[m][l][k]
// Output xs bf16 [ck][MRP] (mr-fast), pairs (r=0,1) packed as dword stores.
__global__ __launch_bounds__(256)
void sht_stageA(const float* __restrict__ pct, const unsigned short* __restrict__ xA,
                unsigned short* __restrict__ xs) {
    __shared__ unsigned short As[128 * 32];   // [cr][lq][8] 8KB
    __shared__ unsigned short Bs[32 * 130];   // [l][130]    8.1KB (pad vs conflicts)

    const int m   = blockIdx.y;
    const int ct  = blockIdx.x & 1;           // cr-tile
    const int kt  = blockIdx.x >> 1;          // k-tile 0..2
    const int c0  = ct * 128;
    const int n0  = kt * 128;
    const int t   = threadIdx.x;
    const int w   = t >> 6, L = t & 63;
    const int wr  = w & 1, wc = w >> 1;
    const int lane15 = L & 15, quad = L >> 4;
    const int bl = t >> 3, bkq = t & 7;       // B-staging roles

    const unsigned short* xAm = xA + (size_t)m * CR * LP;
    const float* pctm = pct + (size_t)m * LDIM * KDIM;

    floatx4 acc[4][4] = {};

    for (int kb = 0; kb < LP; kb += 32) {
        // A tile: global_load_lds, slot s -> cr=s>>2, lq=s&3
        #pragma unroll
        for (int i = 0; i < 2; ++i) {
            int s = w * 128 + i * 64 + L;
            int cr = s >> 2, lq = s & 3;
            async_copy16(xAm + (size_t)(c0 + cr) * LP + kb + lq * 8,
                         As + (size_t)(w * 128 + i * 64) * 8);
        }
        // B tile: pct rows l=kb+bl, cols n0 + u*32 + bkq*4 + 0..3 (guarded), cvt bf16
        {
            int l = kb + bl;
            bool lok = (l < LDIM);
            const float* prow = pctm + (size_t)l * KDIM;
            #pragma unroll
            for (int u = 0; u < 4; ++u) {
                int kc = n0 + u * 32 + bkq * 4;
                float f0 = (lok && kc + 0 < KDIM) ? prow[kc + 0] : 0.f;
                float f1 = (lok && kc + 1 < KDIM) ? prow[kc + 1] : 0.f;
                float f2 = (lok && kc + 2 < KDIM) ? prow[kc + 2] : 0.f;
                float f3 = (lok && kc + 3 < KDIM) ? prow[kc + 3] : 0.f;
                unsigned* bp = (unsigned*)&Bs[bl * 130 + u * 32 + bkq * 4];
                bp[0] = (unsigned)f2bf(f0) | ((unsigned)f2bf(f1) << 16);
                bp[1] = (unsigned)f2bf(f2) | ((unsigned)f2bf(f3) << 16);
            }
        }
        __syncthreads();

        short8 af[4];
        #pragma unroll
        for (int i = 0; i < 4; ++i) {
            int row = wr * 64 + i * 16 + lane15;
            af[i] = *(const short8*)&As[(row * 4 + quad) * 8];
        }
        #pragma unroll
        for (int jf = 0; jf < 4; ++jf) {
            int col = wc * 64 + jf * 16 + lane15;
            short8 bf;
            #pragma unroll
            for (int j = 0; j < 8; ++j)
                bf[j] = (short)Bs[(quad * 8 + j) * 130 + col];
            #pragma unroll
            for (int i = 0; i < 4; ++i)
                acc[i][jf] = __builtin_amdgcn_mfma_f32_16x16x32_bf16(af[i], bf, acc[i][jf], 0, 0, 0);
        }
        __syncthreads();
    }

    // epilogue: element (cr,k): c=cr>>1, r=cr&1 -> xs[(c*361+k)*736 + 2m+r]
    #pragma unroll
    for (int i = 0; i < 4; ++i) {
        #pragma unroll
        for (int jf = 0; jf < 4; ++jf) {
            int k = n0 + wc * 64 + jf * 16 + lane15;
            if (k >= KDIM) continue;
            #pragma unroll
            for (int eh = 0; eh < 2; ++eh) {
                int cr = c0 + wr * 64 + i * 16 + quad * 4 + eh * 2;  // even
                int c  = cr >> 1;
                unsigned pack = (unsigned)f2bf(acc[i][jf][eh * 2]) |
                                ((unsigned)f2bf(acc[i][jf][eh * 2 + 1]) << 16);
                *(unsigned*)(xs + (size_t)(c * KDIM + k) * MRP + 2 * m) = pack;
            }
        }
    }
}

// ---------------------------------------------------------------------------
// Stage B: out[ck][j] = sum_mr xs[ck][mr] * Tp[j][mr]   (m97 structure, no guards in K-loop)
__global__ __launch_bounds__(256)
void sht_stageB(const unsigned short* __restrict__ xs, const unsigned short* __restrict__ Tp,
                float* __restrict__ out) {
    __shared__ unsigned short As[128 * 32];   // [ck][mq][8] 8KB
    __shared__ unsigned short Bs[128 * 32];   // [n][mq][8]  8KB

    const int nt  = blockIdx.x;               // 0..5
    const int ckt = blockIdx.y;               // 0..360
    const int ck0 = ckt * 128, n0 = nt * 128;
    const int t   = threadIdx.x;
    const int w   = t >> 6, L = t & 63;
    const int wr  = w & 1, wc = w >> 1;
    const int lane15 = L & 15, quad = L >> 4;

    floatx4 acc[4][4] = {};

    for (int kb = 0; kb < MRP; kb += 32) {
        #pragma unroll
        for (int i = 0; i < 2; ++i) {
            int s = w * 128 + i * 64 + L;
            int rr = s >> 2, mq = s & 3;
            async_copy16(xs + (size_t)(ck0 + rr) * MRP + kb + mq * 8,
                         As + (size_t)(w * 128 + i * 64) * 8);
            async_copy16(Tp + (size_t)(n0 + rr) * MRP + kb + mq * 8,
                         Bs + (size_t)(w * 128 + i * 64) * 8);
        }
        __syncthreads();

        short8 af[4], bfr[4];
        #pragma unroll
        for (int i = 0; i < 4; ++i)
            af[i] = *(const short8*)&As[((wr * 64 + i * 16 + lane15) * 4 + quad) * 8];
        #pragma unroll
        for (int jf = 0; jf < 4; ++jf)
            bfr[jf] = *(const short8*)&Bs[((wc * 64 + jf * 16 + lane15) * 4 + quad) * 8];
        #pragma unroll
        for (int i = 0; i < 4; ++i)
            #pragma unroll
            for (int jf = 0; jf < 4; ++jf)
                acc[i][jf] = __builtin_amdgcn_mfma_f32_16x16x32_bf16(af[i], bfr[jf], acc[i][jf], 0, 0, 0);
        __syncthreads();
    }

    #pragma unroll
    for (int i = 0; i < 4; ++i) {
        int ckr = ck0 + wr * 64 + i * 16 + quad * 4;
        #pragma unroll
        for (int jf = 0; jf < 4; ++jf) {
            int j = n0 + wc * 64 + jf * 16 + lane15;
            if (j >= NLON) continue;
            #pragma unroll
            for (int e = 0; e < 4; ++e)
                out[(size_t)(ckr + e) * NLON + j] = acc[i][jf][e];
        }
    }
}

// ---------------------------------------------------------------------------
extern "C" void kernel_launch(void* const* d_in, const int* in_sizes, int n_in,
                              void* d_out, int out_size, void* d_ws, size_t ws_size,
                              hipStream_t stream) {
    const float* x   = (const float*)d_in[0];   // [1,128,361,361,2] fp32
    const float* pct = (const float*)d_in[1];   // [361,361,361] fp32
    float* out = (float*)d_out;                 // [1,128,361,720] fp32

    unsigned short* xs = (unsigned short*)d_ws;              // CK*MRP bf16 (68.0 MB)
    unsigned short* Tp = xs + (size_t)CK * MRP;              // NP*MRP bf16 (1.13 MB)
    unsigned short* xA = (unsigned short*)d_out;             // 361*256*384 bf16 (71 MB, dead before stage B)

    sht_gen_T<<<(NP * MRP + 255) / 256, 256, 0, stream>>>(Tp);
    sht_prep_x<<<dim3(12, 6, 128), 256, 0, stream>>>(x, xA);
    sht_stageA<<<dim3(6, MDIM), 256, 0, stream>>>(pct, xA, xs);
    sht_stageB<<<dim3(6, MDIM), 256, 0, stream>>>(xs, Tp, out);
}